// Round 1
// baseline (292.381 us; speedup 1.0000x reference)
//
#include <hip/hip_runtime.h>
#include <math.h>

#define FIN 128
#define FOUT 64
#define MAXDEG 64
#define BKT_SHIFT 7           // 128 dsts per bucket
#define BKT_CAP 2560          // mean 2048, +11 sigma

// ---------------- helpers ----------------

__device__ __forceinline__ float4 f4add(float4 a, float4 b) {
  return make_float4(a.x + b.x, a.y + b.y, a.z + b.z, a.w + b.w);
}
__device__ __forceinline__ float4 f4fma(float c, float4 v, float4 a) {
  return make_float4(fmaf(c, v.x, a.x), fmaf(c, v.y, a.y),
                     fmaf(c, v.z, a.z), fmaf(c, v.w, a.w));
}
__device__ __forceinline__ float4 f4shflxor(float4 v, int off) {
  return make_float4(__shfl_xor(v.x, off, 64), __shfl_xor(v.y, off, 64),
                     __shfl_xor(v.z, off, 64), __shfl_xor(v.w, off, 64));
}
__device__ __forceinline__ float red16(float v) {
  v += __shfl_xor(v, 1, 64);
  v += __shfl_xor(v, 2, 64);
  v += __shfl_xor(v, 4, 64);
  v += __shfl_xor(v, 8, 64);
  return v;
}
__device__ __forceinline__ float wave_sum(float v) {
#pragma unroll
  for (int off = 1; off <= 32; off <<= 1) v += __shfl_xor(v, off, 64);
  return v;
}

// logmap0 row factor: artanh(clip(n))/max(n,1e-15), c=1
__device__ __forceinline__ float row_scale(float ss) {
  float n  = sqrtf(ss);
  float nc = fmaxf(n, 1e-15f);
  float t  = fminf(nc, 1.0f - 1e-7f);
  float at = 0.5f * (log1pf(t) - log1pf(-t));
  return at / nc;
}

__device__ __forceinline__ float leaky(float v) {
  return (v >= 0.f) ? v : 0.01f * v;
}

// bf16 pack (RNE) / unpack uint2 -> 4 floats
__device__ __forceinline__ unsigned int bf16rne(float x) {
  unsigned int b = __float_as_uint(x);
  b += 0x7FFFu + ((b >> 16) & 1u);
  return b >> 16;
}
__device__ __forceinline__ float4 bf4(uint2 v) {
  return make_float4(__uint_as_float(v.x << 16),
                     __uint_as_float(v.x & 0xFFFF0000u),
                     __uint_as_float(v.y << 16),
                     __uint_as_float(v.y & 0xFFFF0000u));
}

// ---------------- kernel 1: [gemm 128-node tiles, 2 k-phases] U [binA] ------
// LDS cut 68KB -> 36KB (4 blocks/CU instead of 2) by staging K in two 64-wide
// phases; phase-1 global loads issued into registers before phase-0 compute.
__global__ __launch_bounds__(256) void k_main(const float* __restrict__ x,
                                              const float* __restrict__ Wup,
                                              const float* __restrict__ Wpl,
                                              const float* __restrict__ Wlw,
                                              float* __restrict__ u,
                                              float* __restrict__ scl4,
                                              const int* __restrict__ ei, int E,
                                              int nb, int* __restrict__ bcnt,
                                              int2* __restrict__ stg,
                                              int N, int gemmBlocks) {
  __shared__ float buf[128 * 67];  // 34.3KB: xs 2 tiles x 64k x 64n (8192 fl) / us[n*67+f]; binA hist+base
  __shared__ float wls[256];
  __shared__ float ps[256];
  __shared__ float scl[128];

  int t = threadIdx.x;

  if (blockIdx.x >= gemmBlocks) {
    // ================= binA branch =================
    int* hist = (int*)buf;
    int* base = hist + nb;
    int bb = blockIdx.x - gemmBlocks;
    for (int h = t; h < nb; h += 256) hist[h] = 0;
    __syncthreads();
    int e0 = bb * 4096 + t * 16;
    int sv[16], dv[16];
#pragma unroll
    for (int j = 0; j < 16; j += 4) {
      int e = e0 + j;
      if (e + 3 < E) {
        int4 s4 = *(const int4*)(ei + e);
        int4 d4 = *(const int4*)(ei + E + e);
        sv[j] = s4.x; sv[j+1] = s4.y; sv[j+2] = s4.z; sv[j+3] = s4.w;
        dv[j] = d4.x; dv[j+1] = d4.y; dv[j+2] = d4.z; dv[j+3] = d4.w;
      } else {
        for (int q = 0; q < 4; ++q) {
          int ee = e + q;
          sv[j+q] = (ee < E) ? ei[ee] : -1;
          dv[j+q] = (ee < E) ? ei[E + ee] : -1;
        }
      }
    }
#pragma unroll
    for (int j = 0; j < 16; ++j)
      if (dv[j] >= 0) atomicAdd(&hist[dv[j] >> BKT_SHIFT], 1);
    __syncthreads();
    for (int h = t; h < nb; h += 256)
      base[h] = hist[h] ? atomicAdd(&bcnt[h], hist[h]) : 0;
    __syncthreads();
    for (int h = t; h < nb; h += 256) hist[h] = 0;
    __syncthreads();
#pragma unroll
    for (int j = 0; j < 16; ++j) {
      if (dv[j] < 0) continue;
      int b = dv[j] >> BKT_SHIFT;
      int p = base[b] + atomicAdd(&hist[b], 1);
      if (p < BKT_CAP) stg[(size_t)b * BKT_CAP + p] = make_int2(sv[j], dv[j]);
    }
    return;
  }

  // ================= gemm branch: 128 nodes/block, 2 K-phases =============
  int n0 = blockIdx.x * 128;
  {
    int proj = t >> 6, f = t & 63;
    float wv = (proj == 0) ? Wpl[f * 2]
             : (proj == 1) ? Wpl[f * 2 + 1]
             : (proj == 2) ? Wlw[f] : Wlw[64 + f];
    wls[t] = wv;
  }

  int n    = t & 127;
  int khal = t >> 7;              // 2 threads/node, each owns 8 float4/phase
  int gn = n0 + n;
  bool ok = gn < N;
  const float4* xr = (const float4*)(x + (size_t)gn * FIN);
  float* xb = buf + (n >> 6) * 4096;
  int nl = n & 63;

  int wave = t >> 6, lane = t & 63;
  int tile = wave >> 1, half = wave & 1;
  int i = lane & 7, j = lane >> 3;
  const float* xp = buf + tile * 4096 + i * 8;
  const float* wg = Wup + half * 32 + j * 4;
  float4 a0 = make_float4(0,0,0,0), a1 = a0, a2 = a0, a3 = a0;
  float4 a4 = a0, a5 = a0, a6 = a0, a7 = a0;
  float ssum = 0.f;

  float4 r0[8], r1[8];
#pragma unroll
  for (int m = 0; m < 8; ++m) {    // phase-0 loads (k float4 idx 0..15)
    int kcg = khal * 8 + m;
    r0[m] = ok ? xr[kcg] : make_float4(0.f, 0.f, 0.f, 0.f);
  }
#pragma unroll
  for (int m = 0; m < 8; ++m) {    // stage phase 0 + norm partial
    float4 v = r0[m];
    ssum = fmaf(v.x, v.x, fmaf(v.y, v.y, fmaf(v.z, v.z, fmaf(v.w, v.w, ssum))));
    int kl = (khal * 8 + m) * 4;
    xb[(kl + 0) * 64 + nl] = v.x;
    xb[(kl + 1) * 64 + nl] = v.y;
    xb[(kl + 2) * 64 + nl] = v.z;
    xb[(kl + 3) * 64 + nl] = v.w;
  }
#pragma unroll
  for (int m = 0; m < 8; ++m) {    // phase-1 loads issued early (in flight)
    int kcg = 16 + khal * 8 + m;
    r1[m] = ok ? xr[kcg] : make_float4(0.f, 0.f, 0.f, 0.f);
  }
  __syncthreads();                 // S1: xs phase 0 ready

#pragma unroll 8
  for (int k = 0; k < 64; ++k) {   // gemm phase 0
    float4 xv0 = *(const float4*)(xp + k * 64);
    float4 xv1 = *(const float4*)(xp + k * 64 + 4);
    float4 wv = *(const float4*)(wg + k * 64);
    a0 = f4fma(xv0.x, wv, a0);
    a1 = f4fma(xv0.y, wv, a1);
    a2 = f4fma(xv0.z, wv, a2);
    a3 = f4fma(xv0.w, wv, a3);
    a4 = f4fma(xv1.x, wv, a4);
    a5 = f4fma(xv1.y, wv, a5);
    a6 = f4fma(xv1.z, wv, a6);
    a7 = f4fma(xv1.w, wv, a7);
  }
  __syncthreads();                 // S2: phase-0 xs dead

#pragma unroll
  for (int m = 0; m < 8; ++m) {    // stage phase 1 + norm partial
    float4 v = r1[m];
    ssum = fmaf(v.x, v.x, fmaf(v.y, v.y, fmaf(v.z, v.z, fmaf(v.w, v.w, ssum))));
    int kl = (khal * 8 + m) * 4;
    xb[(kl + 0) * 64 + nl] = v.x;
    xb[(kl + 1) * 64 + nl] = v.y;
    xb[(kl + 2) * 64 + nl] = v.z;
    xb[(kl + 3) * 64 + nl] = v.w;
  }
  ps[t] = ssum;
  __syncthreads();                 // S3: xs phase 1 + ps ready
  if (t < 128) scl[t] = row_scale(ps[t] + ps[t + 128]);

#pragma unroll 8
  for (int k = 0; k < 64; ++k) {   // gemm phase 1
    float4 xv0 = *(const float4*)(xp + k * 64);
    float4 xv1 = *(const float4*)(xp + k * 64 + 4);
    float4 wv = *(const float4*)(wg + (64 + k) * 64);
    a0 = f4fma(xv0.x, wv, a0);
    a1 = f4fma(xv0.y, wv, a1);
    a2 = f4fma(xv0.z, wv, a2);
    a3 = f4fma(xv0.w, wv, a3);
    a4 = f4fma(xv1.x, wv, a4);
    a5 = f4fma(xv1.y, wv, a5);
    a6 = f4fma(xv1.z, wv, a6);
    a7 = f4fma(xv1.w, wv, a7);
  }
  __syncthreads();                 // S4: xs dead, scl ready; buf -> us[n*67+f]

  int fbase = half * 32 + j * 4;
#pragma unroll
  for (int r = 0; r < 8; ++r) {
    float4 acc = (r==0)?a0:(r==1)?a1:(r==2)?a2:(r==3)?a3:(r==4)?a4:(r==5)?a5:(r==6)?a6:a7;
    int nn = tile * 64 + i * 8 + r;
    int gnn = n0 + nn;
    float sc = scl[nn];
    float4 o = make_float4(leaky(sc * acc.x), leaky(sc * acc.y),
                           leaky(sc * acc.z), leaky(sc * acc.w));
    if (gnn < N) *(float4*)(u + (size_t)gnn * FOUT + fbase) = o;
    buf[nn * 67 + fbase]     = o.x;    // stride 67
    buf[nn * 67 + fbase + 1] = o.y;
    buf[nn * 67 + fbase + 2] = o.z;
    buf[nn * 67 + fbase + 3] = o.w;
  }
  __syncthreads();

  {
    int proj = t >> 6;
    const float* wc = wls + proj * 64;
#pragma unroll
    for (int rep = 0; rep < 2; ++rep) {
      int nn = (t & 63) + rep * 64;
      int gnn = n0 + nn;
      const float* ur = buf + nn * 67;   // (3n+f)%32: conflict-free across lanes
      float acc = 0.f;
#pragma unroll 8
      for (int f = 0; f < 64; ++f) acc = fmaf(ur[f], wc[f], acc);
      if (gnn < N) scl4[(size_t)gnn * 4 + proj] = acc;
    }
  }
}

// ---------------- kernel 2: per-bucket CSR placement + sentinel padding -----
__global__ __launch_bounds__(256) void k_binB(const int2* __restrict__ stg,
                                              const int* __restrict__ bcnt,
                                              int N, int* __restrict__ deg,
                                              int* __restrict__ slots) {
  __shared__ int cur[128];
  int b = blockIdx.x, t = threadIdx.x;
  if (t < 128) cur[t] = 0;
  __syncthreads();
  int cnt = min(bcnt[b], BKT_CAP);
  int dbase = b << BKT_SHIFT;
  const int2* sp = stg + (size_t)b * BKT_CAP;
  for (int i = t; i < cnt; i += 256) {
    int2 e = sp[i];
    int p = atomicAdd(&cur[e.y - dbase], 1);
    if (p < MAXDEG) slots[(size_t)e.y * MAXDEG + p] = e.x;
  }
  __syncthreads();
  if (t < 128) {
    int dst = dbase + t;
    if (dst < N) {
      int c = min(cur[t], MAXDEG);
      deg[dst] = c;
      int cr = (c + 15) & ~15;
      for (int p = c; p < cr; ++p) slots[(size_t)dst * MAXDEG + p] = N;
    }
  }
}

// ---------------- kernel 3a: gate phase (scalar gather, 16 B/edge) ----------
// slots load predicated on lane<d: skips ~55% of the 256 B row sectors.
__global__ __launch_bounds__(256) void k_aggA(const int* __restrict__ deg,
                                              const int* __restrict__ slots,
                                              const float4* __restrict__ scl4,
                                              float* __restrict__ selF,
                                              float* __restrict__ gq,
                                              float* __restrict__ tp, int N) {
  int wv = threadIdx.x >> 6, lane = threadIdx.x & 63;
  int i = blockIdx.x * 4 + wv;
  if (i >= N) return;
  int d = deg[i];
  bool valid = lane < d;
  int s = 0;
  if (valid) s = slots[(size_t)i * MAXDEG + lane];
  float4 g = scl4[s];
  float sp0 = wave_sum(valid ? g.x : 0.f);
  float sp1 = wave_sum(valid ? g.y : 0.f);
  float sq2 = wave_sum(valid ? g.w : 0.f);
  float r0 = fmaxf(sp0, 0.f), r1 = fmaxf(sp1, 0.f);
  float m  = fmaxf(r0, r1);
  float e0 = expf(r0 - m), e1 = expf(r1 - m);
  float p  = e1 / (e0 + e1);
  float sel = (p > 0.48f) ? 1.f : 0.f;
  if (lane == 0) {
    float4 own = scl4[i];
    selF[i] = sel;
    gq[i]   = sel * own.z;   // selF[i] * q1[i]
    tp[i]   = sq2;           // sum_neigh . Wlw[64:]
  }
}

// ---------------- kernel 3b: weight phase + bf16 uw materialization ---------
// u-read skipped (wave-uniform) for unselected nodes: uw row is zero anyway.
__global__ __launch_bounds__(256) void k_aggB(const int* __restrict__ deg,
                                              const int* __restrict__ slots,
                                              const float* __restrict__ gq,
                                              const float* __restrict__ tp,
                                              const float* __restrict__ selF,
                                              const float* __restrict__ u,
                                              unsigned int* __restrict__ uw,
                                              int N) {
  if (blockIdx.x == 0 && threadIdx.x < 32)      // zero sentinel row N
    uw[(size_t)N * 32 + threadIdx.x] = 0u;
  int wv = threadIdx.x >> 6, lane = threadIdx.x & 63;
  int i = blockIdx.x * 4 + wv;
  if (i >= N) return;
  int d = deg[i];
  bool valid = lane < d;
  int s = 0;
  if (valid) s = slots[(size_t)i * MAXDEG + lane];
  float v = gq[s];
  float t = tp[i] + wave_sum(valid ? v : 0.f);
  float seli = selF[i];
  float val = 0.f;
  if (seli != 0.f) {                   // wave-uniform branch
    float sig = 1.f / (1.f + expf(-t));
    val = sig * u[(size_t)i * 64 + lane];
  }
  unsigned int b = bf16rne(val);
  unsigned int partner = (unsigned int)__shfl_xor((int)b, 1, 64);
  if ((lane & 1) == 0)
    uw[(size_t)i * 32 + (lane >> 1)] = (b & 0xFFFFu) | (partner << 16);
}

// ---------------- kernel 3c: vector phase — ballot-compacted uw gather ------
__global__ __launch_bounds__(256) void k_agg3(const int* __restrict__ deg,
                                              const int* __restrict__ slots,
                                              const float* __restrict__ selF,
                                              const float* __restrict__ u,
                                              const uint2* __restrict__ uw,
                                              float* __restrict__ out, int N) {
  __shared__ int comp[4][64];
  int wv = threadIdx.x >> 6, lane = threadIdx.x & 63;
  int i = blockIdx.x * 4 + wv;
  if (i >= N) return;
  int d = deg[i];
  bool valid = lane < d;
  int s = 0;
  if (valid) s = slots[(size_t)i * MAXDEG + lane];
  bool flag = valid && (selF[s] != 0.f);
  unsigned long long mask = __ballot(flag);
  int cnt = __popcll(mask);
  comp[wv][lane] = N;                  // sentinel: uw row N is zeroed
  int rank = __popcll(mask & ((1ull << lane) - 1ull));
  if (flag) comp[wv][rank] = s;
  int sub = lane >> 4, l4 = lane & 15;
  float4 acc0 = make_float4(0, 0, 0, 0), acc1 = acc0;
  for (int k0 = 0; k0 < cnt; k0 += 8) {
    int s0 = comp[wv][k0 + sub];
    int s1 = comp[wv][k0 + sub + 4];
    uint2 w0 = uw[(size_t)s0 * 16 + l4];
    uint2 w1 = uw[(size_t)s1 * 16 + l4];
    acc0 = f4add(acc0, bf4(w0));
    acc1 = f4add(acc1, bf4(w1));
  }
  float4 acc = f4add(acc0, acc1);
  acc = f4add(acc, f4shflxor(acc, 16));
  acc = f4add(acc, f4shflxor(acc, 32));
  float4 uv = ((const float4*)(u + (size_t)i * 64))[l4];
  float4 ov = make_float4(uv.x + fmaxf(acc.x, 0.f), uv.y + fmaxf(acc.y, 0.f),
                          uv.z + fmaxf(acc.z, 0.f), uv.w + fmaxf(acc.w, 0.f));
  float ssp = ov.x * ov.x + ov.y * ov.y + ov.z * ov.z + ov.w * ov.w;
  float ss  = red16(ssp);
  float nc  = fmaxf(sqrtf(ss), 1e-15f);
  float th  = tanhf(nc);
  float fac = th / nc;
  float4 r = make_float4(ov.x * fac, ov.y * fac, ov.z * fac, ov.w * fac);
  float n2 = fmaxf(th, 1e-15f);
  float maxn = 1.0f - 4e-3f;
  float sc = (n2 > maxn) ? (maxn / n2) : 1.0f;
  float4 res = make_float4(r.x * sc, r.y * sc, r.z * sc, r.w * sc);
  if (sub == 0) ((float4*)(out + (size_t)i * 64))[l4] = res;
}

// ---------------- launch ----------------
extern "C" void kernel_launch(void* const* d_in, const int* in_sizes, int n_in,
                              void* d_out, int out_size, void* d_ws, size_t ws_size,
                              hipStream_t stream) {
  const float* x   = (const float*)d_in[0];
  const int*   ei  = (const int*)d_in[1];
  const float* Wup = (const float*)d_in[2];
  const float* Wpl = (const float*)d_in[3];
  const float* Wlw = (const float*)d_in[4];
  float* out = (float*)d_out;

  int N = in_sizes[0] / FIN;     // 100000
  int E = in_sizes[1] / 2;       // 1600000
  int nb = (N + (1 << BKT_SHIFT) - 1) >> BKT_SHIFT;   // 782 buckets

  char* ws = (char*)d_ws;
  float* u     = (float*)ws;                            // 25.6 MB
  int*   slots = (int*)(u + (size_t)N * 64);            // 25.6 MB
  char*  regB  = (char*)(slots + (size_t)N * MAXDEG);   // union: stg | uw
  size_t regB_sz = (size_t)nb * BKT_CAP * sizeof(int2); // 16.0 MB
  int2*  stg   = (int2*)regB;               // lifetime: k_main(binA) -> binB
  unsigned int* uwp = (unsigned int*)regB;  // lifetime: aggB -> agg3
  float* scl4  = (float*)(regB + regB_sz);              // 1.6 MB
  int*   deg   = (int*)(scl4 + (size_t)N * 4);          // 0.4 MB
  float* selF  = (float*)(deg + N);                     // 0.4 MB
  float* gq    = selF + N;                              // 0.4 MB
  float* tp    = gq + N;                                // 0.4 MB
  int*   bcnt  = (int*)(tp + N);                        // tiny

  hipMemsetAsync(bcnt, 0, nb * sizeof(int), stream);

  int gemmBlocks = (N + 127) / 128;               // 782
  int binABlocks = (E + 4095) / 4096;             // 391
  k_main<<<gemmBlocks + binABlocks, 256, 0, stream>>>(
      x, Wup, Wpl, Wlw, u, scl4, ei, E, nb, bcnt, stg, N, gemmBlocks);
  k_binB<<<nb, 256, 0, stream>>>(stg, bcnt, N, deg, slots);
  int nblk = (N + 3) / 4;
  k_aggA<<<nblk, 256, 0, stream>>>(deg, slots, (const float4*)scl4, selF, gq, tp, N);
  k_aggB<<<nblk, 256, 0, stream>>>(deg, slots, gq, tp, selF, u, uwp, N);
  k_agg3<<<nblk, 256, 0, stream>>>(deg, slots, selF, u, (const uint2*)uwp, out, N);
}

// Round 2
// 243.524 us; speedup vs baseline: 1.2006x; 1.2006x over previous
//
#include <hip/hip_runtime.h>
#include <math.h>

#define FIN 128
#define FOUT 64
#define MAXDEG 64
#define BKT_SHIFT 7           // 128 dsts per bucket
#define BKT_CAP 2560          // mean 2048, +11 sigma

// ---------------- helpers ----------------

__device__ __forceinline__ float4 f4add(float4 a, float4 b) {
  return make_float4(a.x + b.x, a.y + b.y, a.z + b.z, a.w + b.w);
}
__device__ __forceinline__ float4 f4fma(float c, float4 v, float4 a) {
  return make_float4(fmaf(c, v.x, a.x), fmaf(c, v.y, a.y),
                     fmaf(c, v.z, a.z), fmaf(c, v.w, a.w));
}
__device__ __forceinline__ float4 f4shflxor(float4 v, int off) {
  return make_float4(__shfl_xor(v.x, off, 64), __shfl_xor(v.y, off, 64),
                     __shfl_xor(v.z, off, 64), __shfl_xor(v.w, off, 64));
}
__device__ __forceinline__ float red16(float v) {
  v += __shfl_xor(v, 1, 64);
  v += __shfl_xor(v, 2, 64);
  v += __shfl_xor(v, 4, 64);
  v += __shfl_xor(v, 8, 64);
  return v;
}
__device__ __forceinline__ float wave_sum(float v) {
#pragma unroll
  for (int off = 1; off <= 32; off <<= 1) v += __shfl_xor(v, off, 64);
  return v;
}

// logmap0 row factor: artanh(clip(n))/max(n,1e-15), c=1
__device__ __forceinline__ float row_scale(float ss) {
  float n  = sqrtf(ss);
  float nc = fmaxf(n, 1e-15f);
  float t  = fminf(nc, 1.0f - 1e-7f);
  float at = 0.5f * (log1pf(t) - log1pf(-t));
  return at / nc;
}

__device__ __forceinline__ float leaky(float v) {
  return (v >= 0.f) ? v : 0.01f * v;
}

// bf16 pack (RNE) / unpack uint2 -> 4 floats
__device__ __forceinline__ unsigned int bf16rne(float x) {
  unsigned int b = __float_as_uint(x);
  b += 0x7FFFu + ((b >> 16) & 1u);
  return b >> 16;
}
__device__ __forceinline__ float4 bf4(uint2 v) {
  return make_float4(__uint_as_float(v.x << 16),
                     __uint_as_float(v.x & 0xFFFF0000u),
                     __uint_as_float(v.y << 16),
                     __uint_as_float(v.y & 0xFFFF0000u));
}

// ---------------- kernel 1: [gemm 64-node tiles, single phase] U [binA] -----
// Round-0 structure (one load burst -> one barrier -> unbroken 128-k FMA loop)
// at half the tile: LDS 68KB -> 35KB (4 blocks/CU), grid 782 -> 1563 gemm
// blocks, per-block critical path halved.
__global__ __launch_bounds__(256) void k_main(const float* __restrict__ x,
                                              const float* __restrict__ Wup,
                                              const float* __restrict__ Wpl,
                                              const float* __restrict__ Wlw,
                                              float* __restrict__ u,
                                              float* __restrict__ scl4,
                                              const int* __restrict__ ei, int E,
                                              int nb, int* __restrict__ bcnt,
                                              int2* __restrict__ stg,
                                              int N, int gemmBlocks) {
  __shared__ float buf[8192];      // xs: 128k x 64n (32KB) / us[n*67+f] (17KB); binA: hist+base
  __shared__ float wls[256];
  __shared__ float ps[256];
  __shared__ float scl[64];

  int t = threadIdx.x;

  if (blockIdx.x >= gemmBlocks) {
    // ================= binA branch =================
    int* hist = (int*)buf;
    int* base = hist + nb;
    int bb = blockIdx.x - gemmBlocks;
    for (int h = t; h < nb; h += 256) hist[h] = 0;
    __syncthreads();
    int e0 = bb * 4096 + t * 16;
    int sv[16], dv[16];
#pragma unroll
    for (int j = 0; j < 16; j += 4) {
      int e = e0 + j;
      if (e + 3 < E) {
        int4 s4 = *(const int4*)(ei + e);
        int4 d4 = *(const int4*)(ei + E + e);
        sv[j] = s4.x; sv[j+1] = s4.y; sv[j+2] = s4.z; sv[j+3] = s4.w;
        dv[j] = d4.x; dv[j+1] = d4.y; dv[j+2] = d4.z; dv[j+3] = d4.w;
      } else {
        for (int q = 0; q < 4; ++q) {
          int ee = e + q;
          sv[j+q] = (ee < E) ? ei[ee] : -1;
          dv[j+q] = (ee < E) ? ei[E + ee] : -1;
        }
      }
    }
#pragma unroll
    for (int j = 0; j < 16; ++j)
      if (dv[j] >= 0) atomicAdd(&hist[dv[j] >> BKT_SHIFT], 1);
    __syncthreads();
    for (int h = t; h < nb; h += 256)
      base[h] = hist[h] ? atomicAdd(&bcnt[h], hist[h]) : 0;
    __syncthreads();
    for (int h = t; h < nb; h += 256) hist[h] = 0;
    __syncthreads();
#pragma unroll
    for (int j = 0; j < 16; ++j) {
      if (dv[j] < 0) continue;
      int b = dv[j] >> BKT_SHIFT;
      int p = base[b] + atomicAdd(&hist[b], 1);
      if (p < BKT_CAP) stg[(size_t)b * BKT_CAP + p] = make_int2(sv[j], dv[j]);
    }
    return;
  }

  // ================= gemm branch: 64 nodes/block, single K phase ==========
  int n0 = blockIdx.x * 64;
  {
    int proj = t >> 6, f = t & 63;
    float wv = (proj == 0) ? Wpl[f * 2]
             : (proj == 1) ? Wpl[f * 2 + 1]
             : (proj == 2) ? Wlw[f] : Wlw[64 + f];
    wls[t] = wv;
  }

  // stage: thread t owns node n = t&63, k-quarter kq = t>>6 (8 float4)
  {
    int n  = t & 63;
    int kq = t >> 6;
    int gn = n0 + n;
    bool ok = gn < N;
    const float4* xr = (const float4*)(x + (size_t)gn * FIN);
    float ssum = 0.f;
    float4 r0[8];
#pragma unroll
    for (int m = 0; m < 8; ++m)
      r0[m] = ok ? xr[kq * 8 + m] : make_float4(0.f, 0.f, 0.f, 0.f);
#pragma unroll
    for (int m = 0; m < 8; ++m) {
      float4 v = r0[m];
      ssum = fmaf(v.x, v.x, fmaf(v.y, v.y, fmaf(v.z, v.z, fmaf(v.w, v.w, ssum))));
      int kf = kq * 32 + m * 4;
      buf[(kf + 0) * 64 + n] = v.x;
      buf[(kf + 1) * 64 + n] = v.y;
      buf[(kf + 2) * 64 + n] = v.z;
      buf[(kf + 3) * 64 + n] = v.w;
    }
    ps[t] = ssum;
  }
  __syncthreads();                 // xs + ps ready
  if (t < 64) scl[t] = row_scale(ps[t] + ps[t + 64] + ps[t + 128] + ps[t + 192]);

  // gemm: wave w owns cols [w*16, w*16+16); lane: j = lane&3 (4 cols),
  // i = lane>>2 (4 nodes). Quad-broadcast x read, 64B-coalesced u store.
  int wave = t >> 6, lane = t & 63;
  int j = lane & 3, i = lane >> 2;
  const float* xp = buf + i * 4;
  const float* wg = Wup + wave * 16 + j * 4;
  float4 a0 = make_float4(0,0,0,0), a1 = a0, a2 = a0, a3 = a0;
#pragma unroll 8
  for (int k = 0; k < FIN; ++k) {
    float4 xv = *(const float4*)(xp + k * 64);
    float4 wv = *(const float4*)(wg + k * 64);
    a0 = f4fma(xv.x, wv, a0);
    a1 = f4fma(xv.y, wv, a1);
    a2 = f4fma(xv.z, wv, a2);
    a3 = f4fma(xv.w, wv, a3);
  }
  __syncthreads();                 // xs dead, scl visible; buf -> us[n*67+f]

  int fbase = wave * 16 + j * 4;
#pragma unroll
  for (int r = 0; r < 4; ++r) {
    float4 acc = (r == 0) ? a0 : (r == 1) ? a1 : (r == 2) ? a2 : a3;
    int nn = i * 4 + r;
    int gnn = n0 + nn;
    float sc = scl[nn];
    float4 o = make_float4(leaky(sc * acc.x), leaky(sc * acc.y),
                           leaky(sc * acc.z), leaky(sc * acc.w));
    if (gnn < N) *(float4*)(u + (size_t)gnn * FOUT + fbase) = o;
    buf[nn * 67 + fbase]     = o.x;    // stride 67: read pass conflict-free
    buf[nn * 67 + fbase + 1] = o.y;
    buf[nn * 67 + fbase + 2] = o.z;
    buf[nn * 67 + fbase + 3] = o.w;
  }
  __syncthreads();

  {
    int proj = t >> 6;
    const float* wc = wls + proj * 64;
    int nn = t & 63;
    int gnn = n0 + nn;
    const float* ur = buf + nn * 67;   // (3n+f)%32: conflict-free across lanes
    float acc = 0.f;
#pragma unroll 8
    for (int f = 0; f < 64; ++f) acc = fmaf(ur[f], wc[f], acc);
    if (gnn < N) scl4[(size_t)gnn * 4 + proj] = acc;
  }
}

// ---------------- kernel 2: per-bucket CSR placement + sentinel padding -----
__global__ __launch_bounds__(256) void k_binB(const int2* __restrict__ stg,
                                              const int* __restrict__ bcnt,
                                              int N, int* __restrict__ deg,
                                              int* __restrict__ slots) {
  __shared__ int cur[128];
  int b = blockIdx.x, t = threadIdx.x;
  if (t < 128) cur[t] = 0;
  __syncthreads();
  int cnt = min(bcnt[b], BKT_CAP);
  int dbase = b << BKT_SHIFT;
  const int2* sp = stg + (size_t)b * BKT_CAP;
  for (int i = t; i < cnt; i += 256) {
    int2 e = sp[i];
    int p = atomicAdd(&cur[e.y - dbase], 1);
    if (p < MAXDEG) slots[(size_t)e.y * MAXDEG + p] = e.x;
  }
  __syncthreads();
  if (t < 128) {
    int dst = dbase + t;
    if (dst < N) {
      int c = min(cur[t], MAXDEG);
      deg[dst] = c;
      int cr = (c + 15) & ~15;
      for (int p = c; p < cr; ++p) slots[(size_t)dst * MAXDEG + p] = N;
    }
  }
}

// ---------------- kernel 3a: gate phase (scalar gather, 16 B/edge) ----------
// slots load predicated on lane<d: skips ~55% of the 256 B row sectors.
__global__ __launch_bounds__(256) void k_aggA(const int* __restrict__ deg,
                                              const int* __restrict__ slots,
                                              const float4* __restrict__ scl4,
                                              float* __restrict__ selF,
                                              float* __restrict__ gq,
                                              float* __restrict__ tp, int N) {
  int wv = threadIdx.x >> 6, lane = threadIdx.x & 63;
  int i = blockIdx.x * 4 + wv;
  if (i >= N) return;
  int d = deg[i];
  bool valid = lane < d;
  int s = 0;
  if (valid) s = slots[(size_t)i * MAXDEG + lane];
  float4 g = scl4[s];
  float sp0 = wave_sum(valid ? g.x : 0.f);
  float sp1 = wave_sum(valid ? g.y : 0.f);
  float sq2 = wave_sum(valid ? g.w : 0.f);
  float r0 = fmaxf(sp0, 0.f), r1 = fmaxf(sp1, 0.f);
  float m  = fmaxf(r0, r1);
  float e0 = expf(r0 - m), e1 = expf(r1 - m);
  float p  = e1 / (e0 + e1);
  float sel = (p > 0.48f) ? 1.f : 0.f;
  if (lane == 0) {
    float4 own = scl4[i];
    selF[i] = sel;
    gq[i]   = sel * own.z;   // selF[i] * q1[i]
    tp[i]   = sq2;           // sum_neigh . Wlw[64:]
  }
}

// ---------------- kernel 3b: weight phase + bf16 uw materialization ---------
// u-read skipped (wave-uniform) for unselected nodes: uw row is zero anyway.
__global__ __launch_bounds__(256) void k_aggB(const int* __restrict__ deg,
                                              const int* __restrict__ slots,
                                              const float* __restrict__ gq,
                                              const float* __restrict__ tp,
                                              const float* __restrict__ selF,
                                              const float* __restrict__ u,
                                              unsigned int* __restrict__ uw,
                                              int N) {
  if (blockIdx.x == 0 && threadIdx.x < 32)      // zero sentinel row N
    uw[(size_t)N * 32 + threadIdx.x] = 0u;
  int wv = threadIdx.x >> 6, lane = threadIdx.x & 63;
  int i = blockIdx.x * 4 + wv;
  if (i >= N) return;
  int d = deg[i];
  bool valid = lane < d;
  int s = 0;
  if (valid) s = slots[(size_t)i * MAXDEG + lane];
  float v = gq[s];
  float t = tp[i] + wave_sum(valid ? v : 0.f);
  float seli = selF[i];
  float val = 0.f;
  if (seli != 0.f) {                   // wave-uniform branch
    float sig = 1.f / (1.f + expf(-t));
    val = sig * u[(size_t)i * 64 + lane];
  }
  unsigned int b = bf16rne(val);
  unsigned int partner = (unsigned int)__shfl_xor((int)b, 1, 64);
  if ((lane & 1) == 0)
    uw[(size_t)i * 32 + (lane >> 1)] = (b & 0xFFFFu) | (partner << 16);
}

// ---------------- kernel 3c: vector phase — ballot-compacted uw gather ------
__global__ __launch_bounds__(256) void k_agg3(const int* __restrict__ deg,
                                              const int* __restrict__ slots,
                                              const float* __restrict__ selF,
                                              const float* __restrict__ u,
                                              const uint2* __restrict__ uw,
                                              float* __restrict__ out, int N) {
  __shared__ int comp[4][64];
  int wv = threadIdx.x >> 6, lane = threadIdx.x & 63;
  int i = blockIdx.x * 4 + wv;
  if (i >= N) return;
  int d = deg[i];
  bool valid = lane < d;
  int s = 0;
  if (valid) s = slots[(size_t)i * MAXDEG + lane];
  bool flag = valid && (selF[s] != 0.f);
  unsigned long long mask = __ballot(flag);
  int cnt = __popcll(mask);
  comp[wv][lane] = N;                  // sentinel: uw row N is zeroed
  int rank = __popcll(mask & ((1ull << lane) - 1ull));
  if (flag) comp[wv][rank] = s;
  int sub = lane >> 4, l4 = lane & 15;
  float4 acc0 = make_float4(0, 0, 0, 0), acc1 = acc0;
  for (int k0 = 0; k0 < cnt; k0 += 8) {
    int s0 = comp[wv][k0 + sub];
    int s1 = comp[wv][k0 + sub + 4];
    uint2 w0 = uw[(size_t)s0 * 16 + l4];
    uint2 w1 = uw[(size_t)s1 * 16 + l4];
    acc0 = f4add(acc0, bf4(w0));
    acc1 = f4add(acc1, bf4(w1));
  }
  float4 acc = f4add(acc0, acc1);
  acc = f4add(acc, f4shflxor(acc, 16));
  acc = f4add(acc, f4shflxor(acc, 32));
  float4 uv = ((const float4*)(u + (size_t)i * 64))[l4];
  float4 ov = make_float4(uv.x + fmaxf(acc.x, 0.f), uv.y + fmaxf(acc.y, 0.f),
                          uv.z + fmaxf(acc.z, 0.f), uv.w + fmaxf(acc.w, 0.f));
  float ssp = ov.x * ov.x + ov.y * ov.y + ov.z * ov.z + ov.w * ov.w;
  float ss  = red16(ssp);
  float nc  = fmaxf(sqrtf(ss), 1e-15f);
  float th  = tanhf(nc);
  float fac = th / nc;
  float4 r = make_float4(ov.x * fac, ov.y * fac, ov.z * fac, ov.w * fac);
  float n2 = fmaxf(th, 1e-15f);
  float maxn = 1.0f - 4e-3f;
  float sc = (n2 > maxn) ? (maxn / n2) : 1.0f;
  float4 res = make_float4(r.x * sc, r.y * sc, r.z * sc, r.w * sc);
  if (sub == 0) ((float4*)(out + (size_t)i * 64))[l4] = res;
}

// ---------------- launch ----------------
extern "C" void kernel_launch(void* const* d_in, const int* in_sizes, int n_in,
                              void* d_out, int out_size, void* d_ws, size_t ws_size,
                              hipStream_t stream) {
  const float* x   = (const float*)d_in[0];
  const int*   ei  = (const int*)d_in[1];
  const float* Wup = (const float*)d_in[2];
  const float* Wpl = (const float*)d_in[3];
  const float* Wlw = (const float*)d_in[4];
  float* out = (float*)d_out;

  int N = in_sizes[0] / FIN;     // 100000
  int E = in_sizes[1] / 2;       // 1600000
  int nb = (N + (1 << BKT_SHIFT) - 1) >> BKT_SHIFT;   // 782 buckets

  char* ws = (char*)d_ws;
  float* u     = (float*)ws;                            // 25.6 MB
  int*   slots = (int*)(u + (size_t)N * 64);            // 25.6 MB
  char*  regB  = (char*)(slots + (size_t)N * MAXDEG);   // union: stg | uw
  size_t regB_sz = (size_t)nb * BKT_CAP * sizeof(int2); // 16.0 MB
  int2*  stg   = (int2*)regB;               // lifetime: k_main(binA) -> binB
  unsigned int* uwp = (unsigned int*)regB;  // lifetime: aggB -> agg3
  float* scl4  = (float*)(regB + regB_sz);              // 1.6 MB
  int*   deg   = (int*)(scl4 + (size_t)N * 4);          // 0.4 MB
  float* selF  = (float*)(deg + N);                     // 0.4 MB
  float* gq    = selF + N;                              // 0.4 MB
  float* tp    = gq + N;                                // 0.4 MB
  int*   bcnt  = (int*)(tp + N);                        // tiny

  hipMemsetAsync(bcnt, 0, nb * sizeof(int), stream);

  int gemmBlocks = (N + 63) / 64;                 // 1563
  int binABlocks = (E + 4095) / 4096;             // 391
  k_main<<<gemmBlocks + binABlocks, 256, 0, stream>>>(
      x, Wup, Wpl, Wlw, u, scl4, ei, E, nb, bcnt, stg, N, gemmBlocks);
  k_binB<<<nb, 256, 0, stream>>>(stg, bcnt, N, deg, slots);
  int nblk = (N + 3) / 4;
  k_aggA<<<nblk, 256, 0, stream>>>(deg, slots, (const float4*)scl4, selF, gq, tp, N);
  k_aggB<<<nblk, 256, 0, stream>>>(deg, slots, gq, tp, selF, u, uwp, N);
  k_agg3<<<nblk, 256, 0, stream>>>(deg, slots, selF, u, (const uint2*)uwp, out, N);
}

// Round 5
// 232.005 us; speedup vs baseline: 1.2602x; 1.0497x over previous
//
#include <hip/hip_runtime.h>
#include <math.h>

#define FIN 128
#define FOUT 64
#define MAXDEG 64
#define BKT_SHIFT 7           // 128 dsts per bucket
#define BKT_CAP 2560          // mean 2048, +11 sigma

// ---------------- helpers ----------------

__device__ __forceinline__ float4 f4add(float4 a, float4 b) {
  return make_float4(a.x + b.x, a.y + b.y, a.z + b.z, a.w + b.w);
}
__device__ __forceinline__ float4 f4fma(float c, float4 v, float4 a) {
  return make_float4(fmaf(c, v.x, a.x), fmaf(c, v.y, a.y),
                     fmaf(c, v.z, a.z), fmaf(c, v.w, a.w));
}
__device__ __forceinline__ float4 f4shflxor(float4 v, int off) {
  return make_float4(__shfl_xor(v.x, off, 64), __shfl_xor(v.y, off, 64),
                     __shfl_xor(v.z, off, 64), __shfl_xor(v.w, off, 64));
}
__device__ __forceinline__ float red16(float v) {
  v += __shfl_xor(v, 1, 64);
  v += __shfl_xor(v, 2, 64);
  v += __shfl_xor(v, 4, 64);
  v += __shfl_xor(v, 8, 64);
  return v;
}
__device__ __forceinline__ float wave_sum(float v) {
#pragma unroll
  for (int off = 1; off <= 32; off <<= 1) v += __shfl_xor(v, off, 64);
  return v;
}

// logmap0 row factor: artanh(clip(n))/max(n,1e-15), c=1
__device__ __forceinline__ float row_scale(float ss) {
  float n  = sqrtf(ss);
  float nc = fmaxf(n, 1e-15f);
  float t  = fminf(nc, 1.0f - 1e-7f);
  float at = 0.5f * (log1pf(t) - log1pf(-t));
  return at / nc;
}

__device__ __forceinline__ float leaky(float v) {
  return (v >= 0.f) ? v : 0.01f * v;
}

// bf16 pack (RNE) / unpack uint2 -> 4 floats
__device__ __forceinline__ unsigned int bf16rne(float x) {
  unsigned int b = __float_as_uint(x);
  b += 0x7FFFu + ((b >> 16) & 1u);
  return b >> 16;
}
__device__ __forceinline__ float4 bf4(uint2 v) {
  return make_float4(__uint_as_float(v.x << 16),
                     __uint_as_float(v.x & 0xFFFF0000u),
                     __uint_as_float(v.y << 16),
                     __uint_as_float(v.y & 0xFFFF0000u));
}

// ---------------- kernel 1: [gemm 64-node tiles, single phase] U [binA] -----
// f32 vector GEMM (round-2 proven): the x->u->p chain feeds a hard threshold
// (p > 0.48), so the GEMM must stay f32-grade — f16/bf16 MFMA flips gates.
__global__ __launch_bounds__(256) void k_main(const float* __restrict__ x,
                                              const float* __restrict__ Wup,
                                              const float* __restrict__ Wpl,
                                              const float* __restrict__ Wlw,
                                              float* __restrict__ u,
                                              float* __restrict__ scl4,
                                              const int* __restrict__ ei, int E,
                                              int nb, int* __restrict__ bcnt,
                                              int2* __restrict__ stg,
                                              int N, int gemmBlocks) {
  __shared__ float buf[8192];      // xs: 128k x 64n (32KB) / us[n*67+f] (17KB); binA: hist+base
  __shared__ float wls[256];
  __shared__ float ps[256];
  __shared__ float scl[64];

  int t = threadIdx.x;

  if (blockIdx.x >= gemmBlocks) {
    // ================= binA branch =================
    int* hist = (int*)buf;
    int* base = hist + nb;
    int bb = blockIdx.x - gemmBlocks;
    for (int h = t; h < nb; h += 256) hist[h] = 0;
    __syncthreads();
    int e0 = bb * 4096 + t * 16;
    int sv[16], dv[16];
#pragma unroll
    for (int j = 0; j < 16; j += 4) {
      int e = e0 + j;
      if (e + 3 < E) {
        int4 s4 = *(const int4*)(ei + e);
        int4 d4 = *(const int4*)(ei + E + e);
        sv[j] = s4.x; sv[j+1] = s4.y; sv[j+2] = s4.z; sv[j+3] = s4.w;
        dv[j] = d4.x; dv[j+1] = d4.y; dv[j+2] = d4.z; dv[j+3] = d4.w;
      } else {
        for (int q = 0; q < 4; ++q) {
          int ee = e + q;
          sv[j+q] = (ee < E) ? ei[ee] : -1;
          dv[j+q] = (ee < E) ? ei[E + ee] : -1;
        }
      }
    }
#pragma unroll
    for (int j = 0; j < 16; ++j)
      if (dv[j] >= 0) atomicAdd(&hist[dv[j] >> BKT_SHIFT], 1);
    __syncthreads();
    for (int h = t; h < nb; h += 256)
      base[h] = hist[h] ? atomicAdd(&bcnt[h], hist[h]) : 0;
    __syncthreads();
    for (int h = t; h < nb; h += 256) hist[h] = 0;
    __syncthreads();
#pragma unroll
    for (int j = 0; j < 16; ++j) {
      if (dv[j] < 0) continue;
      int b = dv[j] >> BKT_SHIFT;
      int p = base[b] + atomicAdd(&hist[b], 1);
      if (p < BKT_CAP) stg[(size_t)b * BKT_CAP + p] = make_int2(sv[j], dv[j]);
    }
    return;
  }

  // ================= gemm branch: 64 nodes/block, single K phase ==========
  int n0 = blockIdx.x * 64;
  {
    int proj = t >> 6, f = t & 63;
    float wv = (proj == 0) ? Wpl[f * 2]
             : (proj == 1) ? Wpl[f * 2 + 1]
             : (proj == 2) ? Wlw[f] : Wlw[64 + f];
    wls[t] = wv;
  }

  // stage: thread t owns node n = t&63, k-quarter kq = t>>6 (8 float4)
  {
    int n  = t & 63;
    int kq = t >> 6;
    int gn = n0 + n;
    bool ok = gn < N;
    const float4* xr = (const float4*)(x + (size_t)gn * FIN);
    float ssum = 0.f;
    float4 r0[8];
#pragma unroll
    for (int m = 0; m < 8; ++m)
      r0[m] = ok ? xr[kq * 8 + m] : make_float4(0.f, 0.f, 0.f, 0.f);
#pragma unroll
    for (int m = 0; m < 8; ++m) {
      float4 v = r0[m];
      ssum = fmaf(v.x, v.x, fmaf(v.y, v.y, fmaf(v.z, v.z, fmaf(v.w, v.w, ssum))));
      int kf = kq * 32 + m * 4;
      buf[(kf + 0) * 64 + n] = v.x;
      buf[(kf + 1) * 64 + n] = v.y;
      buf[(kf + 2) * 64 + n] = v.z;
      buf[(kf + 3) * 64 + n] = v.w;
    }
    ps[t] = ssum;
  }
  __syncthreads();                 // xs + ps ready
  if (t < 64) scl[t] = row_scale(ps[t] + ps[t + 64] + ps[t + 128] + ps[t + 192]);

  // gemm: wave w owns cols [w*16, w*16+16); lane: j = lane&3 (4 cols),
  // i = lane>>2 (4 nodes). Quad-broadcast x read, 64B-coalesced u store.
  int wave = t >> 6, lane = t & 63;
  int j = lane & 3, i = lane >> 2;
  const float* xp = buf + i * 4;
  const float* wg = Wup + wave * 16 + j * 4;
  float4 a0 = make_float4(0,0,0,0), a1 = a0, a2 = a0, a3 = a0;
#pragma unroll 8
  for (int k = 0; k < FIN; ++k) {
    float4 xv = *(const float4*)(xp + k * 64);
    float4 wv = *(const float4*)(wg + k * 64);
    a0 = f4fma(xv.x, wv, a0);
    a1 = f4fma(xv.y, wv, a1);
    a2 = f4fma(xv.z, wv, a2);
    a3 = f4fma(xv.w, wv, a3);
  }
  __syncthreads();                 // xs dead, scl visible; buf -> us[n*67+f]

  int fbase = wave * 16 + j * 4;
#pragma unroll
  for (int r = 0; r < 4; ++r) {
    float4 acc = (r == 0) ? a0 : (r == 1) ? a1 : (r == 2) ? a2 : a3;
    int nn = i * 4 + r;
    int gnn = n0 + nn;
    float sc = scl[nn];
    float4 o = make_float4(leaky(sc * acc.x), leaky(sc * acc.y),
                           leaky(sc * acc.z), leaky(sc * acc.w));
    if (gnn < N) *(float4*)(u + (size_t)gnn * FOUT + fbase) = o;
    buf[nn * 67 + fbase]     = o.x;    // stride 67: read pass conflict-free
    buf[nn * 67 + fbase + 1] = o.y;
    buf[nn * 67 + fbase + 2] = o.z;
    buf[nn * 67 + fbase + 3] = o.w;
  }
  __syncthreads();

  {
    int proj = t >> 6;
    const float* wc = wls + proj * 64;
    int nn = t & 63;
    int gnn = n0 + nn;
    const float* ur = buf + nn * 67;   // (3n+f)%32: conflict-free across lanes
    float acc = 0.f;
#pragma unroll 8
    for (int f = 0; f < 64; ++f) acc = fmaf(ur[f], wc[f], acc);
    if (gnn < N) scl4[(size_t)gnn * 4 + proj] = acc;
  }
}

// ---------------- kernel 2: per-bucket CSR placement + sentinel padding -----
__global__ __launch_bounds__(256) void k_binB(const int2* __restrict__ stg,
                                              const int* __restrict__ bcnt,
                                              int N, int* __restrict__ deg,
                                              int* __restrict__ slots) {
  __shared__ int cur[128];
  int b = blockIdx.x, t = threadIdx.x;
  if (t < 128) cur[t] = 0;
  __syncthreads();
  int cnt = min(bcnt[b], BKT_CAP);
  int dbase = b << BKT_SHIFT;
  const int2* sp = stg + (size_t)b * BKT_CAP;
  for (int i = t; i < cnt; i += 256) {
    int2 e = sp[i];
    int p = atomicAdd(&cur[e.y - dbase], 1);
    if (p < MAXDEG) slots[(size_t)e.y * MAXDEG + p] = e.x;
  }
  __syncthreads();
  if (t < 128) {
    int dst = dbase + t;
    if (dst < N) {
      int c = min(cur[t], MAXDEG);
      deg[dst] = c;
      int cr = (c + 15) & ~15;
      for (int p = c; p < cr; ++p) slots[(size_t)dst * MAXDEG + p] = N;
    }
  }
}

// ---------------- kernel 3a: gate phase — 16 lanes/node, 16 nodes/block -----
// 4 predicated gather slots per lane issue concurrently (same latency depth
// as the old 64-lane version); red16 is group-local; 4x fewer waves.
__global__ __launch_bounds__(256) void k_aggA(const int* __restrict__ deg,
                                              const int* __restrict__ slots,
                                              const float4* __restrict__ scl4,
                                              float* __restrict__ selF,
                                              float* __restrict__ gq,
                                              float* __restrict__ tp, int N) {
  int wv = threadIdx.x >> 6, lane = threadIdx.x & 63;
  int g = lane >> 4, l16 = lane & 15;
  int i = blockIdx.x * 16 + wv * 4 + g;
  bool act = (i < N);
  int d = act ? deg[i] : 0;
  float ax = 0.f, ay = 0.f, aw = 0.f;
#pragma unroll
  for (int q = 0; q < 4; ++q) {
    int k = l16 + q * 16;
    if (k < d) {
      int s = slots[(size_t)i * MAXDEG + k];
      float4 gg = scl4[s];
      ax += gg.x; ay += gg.y; aw += gg.w;
    }
  }
  ax = red16(ax); ay = red16(ay); aw = red16(aw);
  if (act && l16 == 0) {
    float r0 = fmaxf(ax, 0.f), r1 = fmaxf(ay, 0.f);
    float m  = fmaxf(r0, r1);
    float e0 = expf(r0 - m), e1 = expf(r1 - m);
    float p  = e1 / (e0 + e1);
    float sel = (p > 0.48f) ? 1.f : 0.f;
    float4 own = scl4[i];
    selF[i] = sel;
    gq[i]   = sel * own.z;   // selF[i] * q1[i]
    tp[i]   = aw;            // sum_neigh . Wlw[64:]
  }
}

// ---------------- kernel 3b: weight phase + bf16 uw materialization ---------
// u-read skipped (wave-uniform) for unselected nodes: uw row is zero anyway.
__global__ __launch_bounds__(256) void k_aggB(const int* __restrict__ deg,
                                              const int* __restrict__ slots,
                                              const float* __restrict__ gq,
                                              const float* __restrict__ tp,
                                              const float* __restrict__ selF,
                                              const float* __restrict__ u,
                                              unsigned int* __restrict__ uw,
                                              int N) {
  if (blockIdx.x == 0 && threadIdx.x < 32)      // zero sentinel row N
    uw[(size_t)N * 32 + threadIdx.x] = 0u;
  int wv = threadIdx.x >> 6, lane = threadIdx.x & 63;
  int i = blockIdx.x * 4 + wv;
  if (i >= N) return;
  int d = deg[i];
  bool valid = lane < d;
  int s = 0;
  if (valid) s = slots[(size_t)i * MAXDEG + lane];
  float v = gq[s];
  float t = tp[i] + wave_sum(valid ? v : 0.f);
  float seli = selF[i];
  float val = 0.f;
  if (seli != 0.f) {                   // wave-uniform branch
    float sig = 1.f / (1.f + expf(-t));
    val = sig * u[(size_t)i * 64 + lane];
  }
  unsigned int b = bf16rne(val);
  unsigned int partner = (unsigned int)__shfl_xor((int)b, 1, 64);
  if ((lane & 1) == 0)
    uw[(size_t)i * 32 + (lane >> 1)] = (b & 0xFFFFu) | (partner << 16);
}

// ---------------- kernel 3c: vector phase — ballot-compacted uw gather ------
__global__ __launch_bounds__(256) void k_agg3(const int* __restrict__ deg,
                                              const int* __restrict__ slots,
                                              const float* __restrict__ selF,
                                              const float* __restrict__ u,
                                              const uint2* __restrict__ uw,
                                              float* __restrict__ out, int N) {
  __shared__ int comp[4][64];
  int wv = threadIdx.x >> 6, lane = threadIdx.x & 63;
  int i = blockIdx.x * 4 + wv;
  if (i >= N) return;
  int d = deg[i];
  bool valid = lane < d;
  int s = 0;
  if (valid) s = slots[(size_t)i * MAXDEG + lane];
  bool flag = valid && (selF[s] != 0.f);
  unsigned long long mask = __ballot(flag);
  int cnt = __popcll(mask);
  comp[wv][lane] = N;                  // sentinel: uw row N is zeroed
  int rank = __popcll(mask & ((1ull << lane) - 1ull));
  if (flag) comp[wv][rank] = s;
  int sub = lane >> 4, l4 = lane & 15;
  float4 acc0 = make_float4(0, 0, 0, 0), acc1 = acc0;
  for (int k0 = 0; k0 < cnt; k0 += 8) {
    int s0 = comp[wv][k0 + sub];
    int s1 = comp[wv][k0 + sub + 4];
    uint2 w0 = uw[(size_t)s0 * 16 + l4];
    uint2 w1 = uw[(size_t)s1 * 16 + l4];
    acc0 = f4add(acc0, bf4(w0));
    acc1 = f4add(acc1, bf4(w1));
  }
  float4 acc = f4add(acc0, acc1);
  acc = f4add(acc, f4shflxor(acc, 16));
  acc = f4add(acc, f4shflxor(acc, 32));
  float4 uv = ((const float4*)(u + (size_t)i * 64))[l4];
  float4 ov = make_float4(uv.x + fmaxf(acc.x, 0.f), uv.y + fmaxf(acc.y, 0.f),
                          uv.z + fmaxf(acc.z, 0.f), uv.w + fmaxf(acc.w, 0.f));
  float ssp = ov.x * ov.x + ov.y * ov.y + ov.z * ov.z + ov.w * ov.w;
  float ss  = red16(ssp);
  float nc  = fmaxf(sqrtf(ss), 1e-15f);
  float th  = tanhf(nc);
  float fac = th / nc;
  float4 r = make_float4(ov.x * fac, ov.y * fac, ov.z * fac, ov.w * fac);
  float n2 = fmaxf(th, 1e-15f);
  float maxn = 1.0f - 4e-3f;
  float sc = (n2 > maxn) ? (maxn / n2) : 1.0f;
  float4 res = make_float4(r.x * sc, r.y * sc, r.z * sc, r.w * sc);
  if (sub == 0) ((float4*)(out + (size_t)i * 64))[l4] = res;
}

// ---------------- launch ----------------
extern "C" void kernel_launch(void* const* d_in, const int* in_sizes, int n_in,
                              void* d_out, int out_size, void* d_ws, size_t ws_size,
                              hipStream_t stream) {
  const float* x   = (const float*)d_in[0];
  const int*   ei  = (const int*)d_in[1];
  const float* Wup = (const float*)d_in[2];
  const float* Wpl = (const float*)d_in[3];
  const float* Wlw = (const float*)d_in[4];
  float* out = (float*)d_out;

  int N = in_sizes[0] / FIN;     // 100000
  int E = in_sizes[1] / 2;       // 1600000
  int nb = (N + (1 << BKT_SHIFT) - 1) >> BKT_SHIFT;   // 782 buckets

  char* ws = (char*)d_ws;
  float* u     = (float*)ws;                            // 25.6 MB
  int*   slots = (int*)(u + (size_t)N * 64);            // 25.6 MB
  char*  regB  = (char*)(slots + (size_t)N * MAXDEG);   // union: stg | uw
  size_t regB_sz = (size_t)nb * BKT_CAP * sizeof(int2); // 16.0 MB
  int2*  stg   = (int2*)regB;               // lifetime: k_main(binA) -> binB
  unsigned int* uwp = (unsigned int*)regB;  // lifetime: aggB -> agg3
  float* scl4  = (float*)(regB + regB_sz);              // 1.6 MB
  int*   deg   = (int*)(scl4 + (size_t)N * 4);          // 0.4 MB
  float* selF  = (float*)(deg + N);                     // 0.4 MB
  float* gq    = selF + N;                              // 0.4 MB
  float* tp    = gq + N;                                // 0.4 MB
  int*   bcnt  = (int*)(tp + N);                        // tiny

  hipMemsetAsync(bcnt, 0, nb * sizeof(int), stream);

  int gemmBlocks = (N + 63) / 64;                 // 1563
  int binABlocks = (E + 4095) / 4096;             // 391
  k_main<<<gemmBlocks + binABlocks, 256, 0, stream>>>(
      x, Wup, Wpl, Wlw, u, scl4, ei, E, nb, bcnt, stg, N, gemmBlocks);
  k_binB<<<nb, 256, 0, stream>>>(stg, bcnt, N, deg, slots);
  k_aggA<<<(N + 15) / 16, 256, 0, stream>>>(deg, slots, (const float4*)scl4, selF, gq, tp, N);
  int nblk = (N + 3) / 4;
  k_aggB<<<nblk, 256, 0, stream>>>(deg, slots, gq, tp, selF, u, uwp, N);
  k_agg3<<<nblk, 256, 0, stream>>>(deg, slots, selF, u, (const uint2*)uwp, out, N);
}